// Round 15
// baseline (40.166 us; speedup 1.0000x reference)
//
#include <hip/hip_runtime.h>
#include <hip/hip_bf16.h>

// Problem constants (match reference setup_inputs)
#define BB 64
#define SS 512
#define DD 1024
#define VV 64
#define NSEG (BB * SS)        // 32768
#define THREADS 512
#define WPB (THREADS / 64)    // 8 waves per block, one segment per wave
#define GRID (NSEG / WPB)     // 4096 blocks: blockIdx = (bgroup<<9) | s

typedef float f32x4 __attribute__((ext_vector_type(4)));
typedef unsigned int u32x4 __attribute__((ext_vector_type(4)));

__device__ __forceinline__ ushort f32_to_bf16_rne(float f) {
    unsigned int b = __float_as_uint(f);
    unsigned int r = b + 0x7fffu + ((b >> 16) & 1u);   // round-to-nearest-even
    return (ushort)(r >> 16);
}

// ---------- Pass A: segment start offsets from sorted segment_ids ----------
__global__ __launch_bounds__(256) void fill_bounds_kernel(
    const int* __restrict__ seg_ids,
    int* __restrict__ seg_start,
    int T)
{
    int t = blockIdx.x * blockDim.x + threadIdx.x;
    if (t >= T) return;
    int cur  = seg_ids[t];
    int prev = (t == 0) ? -1 : seg_ids[t - 1];
    for (int s = prev + 1; s <= cur; ++s) seg_start[s] = t;
    if (t == T - 1) {
        for (int s = cur + 1; s <= NSEG; ++s) seg_start[s] = T;
    }
}

// ---------- Pass A2: convert emb table f32 -> bf16 ----------
__global__ __launch_bounds__(256) void conv_emb_kernel(
    const float* __restrict__ emb,
    ushort* __restrict__ tbl)      // [V*D] bf16
{
    const int i = (blockIdx.x * 256 + threadIdx.x) * 4;   // 64 blocks cover 65536 elems
    const f32x4 v = *reinterpret_cast<const f32x4*>(emb + i);
    ushort4 u;
    u.x = f32_to_bf16_rne(v[0]);
    u.y = f32_to_bf16_rne(v[1]);
    u.z = f32_to_bf16_rne(v[2]);
    u.w = f32_to_bf16_rne(v[3]);
    *reinterpret_cast<ushort4*>(tbl + i) = u;
}

// ---------- Pass B: wave-per-segment, scalar control, bf16 16B-lane gather ----------
// VMEM instrs per segment: 2 per token (bf16 row = 2KB = 2 x 64-lane x 16B)
// + 4 stores + amortized pos staging  ->  ~12.5 vs R14's ~20.5.
// Lane l owns cols [l*8, l*8+8) and [512+l*8, 512+l*8+8). Stores are f32x4
// pairs at 32B stride; back-to-back instrs fill each 64B line, plain stores
// let L2 merge (R13: plain ~= NT).
__global__ __launch_bounds__(THREADS) void seg_mean_bf16w_kernel(
    const int* __restrict__ tokens,
    const int* __restrict__ seg_start,  // [NSEG+1]
    const ushort* __restrict__ tbl,     // [V, D] bf16
    const float* __restrict__ pos,      // [S, D]
    float* __restrict__ out)            // [B*S, D]
{
    __shared__ float s_pos[DD];         // 4 KB: the block's shared pos row

    const int tid = threadIdx.x;
    const int bg  = blockIdx.x >> 9;    // 0..7  (b-group of 8 batches)
    const int s   = blockIdx.x & (SS - 1);

    // stage pos[s] once per block
    if (tid < DD / 4) {
        reinterpret_cast<f32x4*>(s_pos)[tid] =
            reinterpret_cast<const f32x4*>(pos + (size_t)s * DD)[tid];
    }
    __syncthreads();

    const int wave = tid >> 6;
    const int lane = tid & 63;
    // wave-uniform seg pinned to SGPR: seg_start/tokens go via s_load (scalar pipe)
    const int seg = __builtin_amdgcn_readfirstlane((bg * WPB + wave) * SS + s);

    const int lo = seg_start[seg];
    const int hi = seg_start[seg + 1];

    const int cA = lane * 8;            // cols [cA, cA+8)
    const int cB = 512 + lane * 8;      // cols [cB, cB+8)

    float accA[8] = {0.f, 0.f, 0.f, 0.f, 0.f, 0.f, 0.f, 0.f};
    float accB[8] = {0.f, 0.f, 0.f, 0.f, 0.f, 0.f, 0.f, 0.f};

    for (int t = lo; t < hi; ++t) {
        const int tok = tokens[t];               // SGPR index -> s_load (K$ hit)
        const ushort* r = tbl + (size_t)tok * DD;
        const u32x4 ua = *reinterpret_cast<const u32x4*>(r + cA);   // 16B = 8 bf16
        const u32x4 ub = *reinterpret_cast<const u32x4*>(r + cB);
        #pragma unroll
        for (int j = 0; j < 4; ++j) {
            accA[2*j]   += __uint_as_float(ua[j] << 16);
            accA[2*j+1] += __uint_as_float(ua[j] & 0xffff0000u);
            accB[2*j]   += __uint_as_float(ub[j] << 16);
            accB[2*j+1] += __uint_as_float(ub[j] & 0xffff0000u);
        }
    }

    const int cnt = hi - lo;
    const float inv = (cnt > 0) ? (1.0f / (float)cnt) : 0.0f;

    // pos from LDS (stride-32B ds_read = 2-way bank alias = free)
    const f32x4 pA0 = *reinterpret_cast<const f32x4*>(s_pos + cA);
    const f32x4 pA1 = *reinterpret_cast<const f32x4*>(s_pos + cA + 4);
    const f32x4 pB0 = *reinterpret_cast<const f32x4*>(s_pos + cB);
    const f32x4 pB1 = *reinterpret_cast<const f32x4*>(s_pos + cB + 4);

    f32x4 oA0, oA1, oB0, oB1;
    #pragma unroll
    for (int j = 0; j < 4; ++j) {
        oA0[j] = accA[j]     * inv + pA0[j];
        oA1[j] = accA[j + 4] * inv + pA1[j];
        oB0[j] = accB[j]     * inv + pB0[j];
        oB1[j] = accB[j + 4] * inv + pB1[j];
    }

    float* orow = out + (size_t)seg * DD;
    *reinterpret_cast<f32x4*>(orow + cA)     = oA0;
    *reinterpret_cast<f32x4*>(orow + cA + 4) = oA1;
    *reinterpret_cast<f32x4*>(orow + cB)     = oB0;
    *reinterpret_cast<f32x4*>(orow + cB + 4) = oB1;
}

// ---------- Fallback (ws too small): binary-search kernel ----------
__device__ __forceinline__ int lower_bound_dev(const int* __restrict__ a, int n, int key) {
    int lo = 0, hi = n;
    while (lo < hi) {
        int mid = (lo + hi) >> 1;
        if (a[mid] < key) lo = mid + 1; else hi = mid;
    }
    return lo;
}

__global__ __launch_bounds__(256) void seg_mean_embed_bsearch_kernel(
    const int* __restrict__ tokens,
    const int* __restrict__ seg_ids,
    const float* __restrict__ emb,
    const float* __restrict__ pos,
    float* __restrict__ out,
    int T)
{
    const int seg = blockIdx.x;
    const int lo = lower_bound_dev(seg_ids, T, seg);
    const int hi = lower_bound_dev(seg_ids, T, seg + 1);
    const int d = threadIdx.x * 4;

    f32x4 acc = (f32x4)(0.f);
    for (int t = lo; t < hi; ++t) {
        const int tok = tokens[t];
        acc += *reinterpret_cast<const f32x4*>(emb + (size_t)tok * DD + d);
    }
    const int cnt = hi - lo;
    const float inv = (cnt > 0) ? (1.0f / (float)cnt) : 0.0f;
    const int s = seg & (SS - 1);
    const f32x4 p = *reinterpret_cast<const f32x4*>(pos + (size_t)s * DD + d);
    f32x4 o = acc * inv + p;
    *reinterpret_cast<f32x4*>(out + (size_t)seg * DD + d) = o;
}

extern "C" void kernel_launch(void* const* d_in, const int* in_sizes, int n_in,
                              void* d_out, int out_size, void* d_ws, size_t ws_size,
                              hipStream_t stream) {
    const int*   tokens  = (const int*)d_in[0];
    const int*   seg_ids = (const int*)d_in[1];
    const float* emb     = (const float*)d_in[2];
    const float* pos     = (const float*)d_in[3];
    float*       out     = (float*)d_out;
    const int T = in_sizes[0];

    // ws layout: [0, 128KB) bf16 emb table; then seg_start
    const size_t tbl_bytes = (size_t)VV * DD * sizeof(ushort);       // 131072
    const size_t need = tbl_bytes + (size_t)(NSEG + 1) * sizeof(int);
    if (ws_size >= need) {
        ushort* tbl       = (ushort*)d_ws;
        int*    seg_start = (int*)((char*)d_ws + tbl_bytes);
        fill_bounds_kernel<<<(T + 255) / 256, 256, 0, stream>>>(seg_ids, seg_start, T);
        conv_emb_kernel<<<(VV * DD) / (256 * 4), 256, 0, stream>>>(emb, tbl);
        seg_mean_bf16w_kernel<<<GRID, THREADS, 0, stream>>>(tokens, seg_start, tbl, pos, out);
    } else {
        seg_mean_embed_bsearch_kernel<<<NSEG, 256, 0, stream>>>(tokens, seg_ids, emb, pos, out, T);
    }
}

// Round 16
// 36.195 us; speedup vs baseline: 1.1097x; 1.1097x over previous
//
#include <hip/hip_runtime.h>
#include <hip/hip_bf16.h>

// Problem constants (match reference setup_inputs)
#define BB 64
#define SS 512
#define DD 1024
#define VV 64
#define NSEG (BB * SS)        // 32768
#define THREADS 512
#define WPB (THREADS / 64)    // 8 waves per block, one segment per wave
#define GRID (NSEG / WPB)     // 4096 blocks: blockIdx = (bgroup<<9) | s

typedef float f32x4 __attribute__((ext_vector_type(4)));
typedef unsigned int u32x4 __attribute__((ext_vector_type(4)));

__device__ __forceinline__ ushort f32_to_bf16_rne(float f) {
    unsigned int b = __float_as_uint(f);
    unsigned int r = b + 0x7fffu + ((b >> 16) & 1u);   // round-to-nearest-even
    return (ushort)(r >> 16);
}

// ---------- Pass A: segment start offsets from sorted segment_ids ----------
__global__ __launch_bounds__(256) void fill_bounds_kernel(
    const int* __restrict__ seg_ids,
    int* __restrict__ seg_start,
    int T)
{
    int t = blockIdx.x * blockDim.x + threadIdx.x;
    if (t >= T) return;
    int cur  = seg_ids[t];
    int prev = (t == 0) ? -1 : seg_ids[t - 1];
    for (int s = prev + 1; s <= cur; ++s) seg_start[s] = t;
    if (t == T - 1) {
        for (int s = cur + 1; s <= NSEG; ++s) seg_start[s] = T;
    }
}

// ---------- Pass A2: convert emb table f32 -> bf16 ----------
__global__ __launch_bounds__(256) void conv_emb_kernel(
    const float* __restrict__ emb,
    ushort* __restrict__ tbl)      // [V*D] bf16
{
    const int i = (blockIdx.x * 256 + threadIdx.x) * 4;   // 64 blocks cover 65536 elems
    const f32x4 v = *reinterpret_cast<const f32x4*>(emb + i);
    ushort4 u;
    u.x = f32_to_bf16_rne(v[0]);
    u.y = f32_to_bf16_rne(v[1]);
    u.z = f32_to_bf16_rne(v[2]);
    u.w = f32_to_bf16_rne(v[3]);
    *reinterpret_cast<ushort4*>(tbl + i) = u;
}

// ---------- Pass B: R14 structure + bf16 gather + end-of-seg shuffle ----------
// Gather: 2 x dwordx4 per token (bf16 row = 2KB), lane owns cols [8l,8l+8) and
// [512+8l,+8). After the loop, ONE cross-lane redistribution (32 shfl, lgkm
// pipe, amortized over the segment) restores R14's d0=lane*4 layout so the
// store stream is bit-identical to R14: 4 x coalesced 1KB NT stores.
// Per-seg VMEM: 8 gather + 4 store + 0.5 pos = 12.5 (R14: 20.5).
__global__ __launch_bounds__(THREADS) void seg_mean_bf16shfl_kernel(
    const int* __restrict__ tokens,
    const int* __restrict__ seg_start,  // [NSEG+1]
    const ushort* __restrict__ tbl,     // [V, D] bf16
    const float* __restrict__ pos,      // [S, D]
    float* __restrict__ out)            // [B*S, D]
{
    __shared__ float s_pos[DD];         // 4 KB: the block's shared pos row

    const int tid = threadIdx.x;
    const int bg  = blockIdx.x >> 9;    // 0..7  (b-group of 8 batches)
    const int s   = blockIdx.x & (SS - 1);

    // stage pos[s] once per block
    if (tid < DD / 4) {
        reinterpret_cast<f32x4*>(s_pos)[tid] =
            reinterpret_cast<const f32x4*>(pos + (size_t)s * DD)[tid];
    }
    __syncthreads();

    const int wave = tid >> 6;
    const int lane = tid & 63;
    // wave-uniform seg pinned to SGPR: seg_start/tokens go via s_load (scalar pipe)
    const int seg = __builtin_amdgcn_readfirstlane((bg * WPB + wave) * SS + s);

    const int lo = seg_start[seg];
    const int hi = seg_start[seg + 1];

    const int c8 = lane * 8;            // accA covers cols [c8, c8+8), accB +512

    float accA[8] = {0.f, 0.f, 0.f, 0.f, 0.f, 0.f, 0.f, 0.f};
    float accB[8] = {0.f, 0.f, 0.f, 0.f, 0.f, 0.f, 0.f, 0.f};

    for (int t = lo; t < hi; ++t) {
        const int tok = tokens[t];               // SGPR index -> s_load (K$ hit)
        const ushort* r = tbl + (size_t)tok * DD;
        const u32x4 ua = *reinterpret_cast<const u32x4*>(r + c8);         // 16B = 8 bf16
        const u32x4 ub = *reinterpret_cast<const u32x4*>(r + 512 + c8);
        #pragma unroll
        for (int j = 0; j < 4; ++j) {
            accA[2*j]   += __uint_as_float(ua[j] << 16);
            accA[2*j+1] += __uint_as_float(ua[j] & 0xffff0000u);
            accB[2*j]   += __uint_as_float(ub[j] << 16);
            accB[2*j+1] += __uint_as_float(ub[j] & 0xffff0000u);
        }
    }

    const int cnt = hi - lo;
    const float inv = (cnt > 0) ? (1.0f / (float)cnt) : 0.0f;

    // ---- one-time cross-lane redistribution to R14 store layout ----
    // Target lane l, quarter q: cols [q*256 + 4l, +4).
    //   q=0: accA from lane l>>1      q=1: accA from lane 32+(l>>1)
    //   q=2: accB from lane l>>1      q=3: accB from lane 32+(l>>1)
    // position in source acc = j + 4*(l&1)  -> shuffle both halves, select.
    const int srcE = lane >> 1;
    const int srcO = 32 + (lane >> 1);
    const bool hi_half = (lane & 1) != 0;
    const int d0 = lane * 4;

    const f32x4 p0 = *reinterpret_cast<const f32x4*>(s_pos + d0);
    const f32x4 p1 = *reinterpret_cast<const f32x4*>(s_pos + d0 + 256);
    const f32x4 p2 = *reinterpret_cast<const f32x4*>(s_pos + d0 + 512);
    const f32x4 p3 = *reinterpret_cast<const f32x4*>(s_pos + d0 + 768);

    f32x4 o0, o1, o2, o3;
    #pragma unroll
    for (int j = 0; j < 4; ++j) {
        const float aLE = __shfl(accA[j],     srcE);
        const float aHE = __shfl(accA[j + 4], srcE);
        const float aLO = __shfl(accA[j],     srcO);
        const float aHO = __shfl(accA[j + 4], srcO);
        const float bLE = __shfl(accB[j],     srcE);
        const float bHE = __shfl(accB[j + 4], srcE);
        const float bLO = __shfl(accB[j],     srcO);
        const float bHO = __shfl(accB[j + 4], srcO);
        o0[j] = (hi_half ? aHE : aLE) * inv + p0[j];
        o1[j] = (hi_half ? aHO : aLO) * inv + p1[j];
        o2[j] = (hi_half ? bHE : bLE) * inv + p2[j];
        o3[j] = (hi_half ? bHO : bLO) * inv + p3[j];
    }

    float* orow = out + (size_t)seg * DD + d0;
    __builtin_nontemporal_store(o0, reinterpret_cast<f32x4*>(orow));
    __builtin_nontemporal_store(o1, reinterpret_cast<f32x4*>(orow + 256));
    __builtin_nontemporal_store(o2, reinterpret_cast<f32x4*>(orow + 512));
    __builtin_nontemporal_store(o3, reinterpret_cast<f32x4*>(orow + 768));
}

// ---------- Fallback (ws too small): binary-search kernel ----------
__device__ __forceinline__ int lower_bound_dev(const int* __restrict__ a, int n, int key) {
    int lo = 0, hi = n;
    while (lo < hi) {
        int mid = (lo + hi) >> 1;
        if (a[mid] < key) lo = mid + 1; else hi = mid;
    }
    return lo;
}

__global__ __launch_bounds__(256) void seg_mean_embed_bsearch_kernel(
    const int* __restrict__ tokens,
    const int* __restrict__ seg_ids,
    const float* __restrict__ emb,
    const float* __restrict__ pos,
    float* __restrict__ out,
    int T)
{
    const int seg = blockIdx.x;
    const int lo = lower_bound_dev(seg_ids, T, seg);
    const int hi = lower_bound_dev(seg_ids, T, seg + 1);
    const int d = threadIdx.x * 4;

    f32x4 acc = (f32x4)(0.f);
    for (int t = lo; t < hi; ++t) {
        const int tok = tokens[t];
        acc += *reinterpret_cast<const f32x4*>(emb + (size_t)tok * DD + d);
    }
    const int cnt = hi - lo;
    const float inv = (cnt > 0) ? (1.0f / (float)cnt) : 0.0f;
    const int s = seg & (SS - 1);
    const f32x4 p = *reinterpret_cast<const f32x4*>(pos + (size_t)s * DD + d);
    f32x4 o = acc * inv + p;
    *reinterpret_cast<f32x4*>(out + (size_t)seg * DD + d) = o;
}

extern "C" void kernel_launch(void* const* d_in, const int* in_sizes, int n_in,
                              void* d_out, int out_size, void* d_ws, size_t ws_size,
                              hipStream_t stream) {
    const int*   tokens  = (const int*)d_in[0];
    const int*   seg_ids = (const int*)d_in[1];
    const float* emb     = (const float*)d_in[2];
    const float* pos     = (const float*)d_in[3];
    float*       out     = (float*)d_out;
    const int T = in_sizes[0];

    // ws layout: [0, 128KB) bf16 emb table; then seg_start
    const size_t tbl_bytes = (size_t)VV * DD * sizeof(ushort);       // 131072
    const size_t need = tbl_bytes + (size_t)(NSEG + 1) * sizeof(int);
    if (ws_size >= need) {
        ushort* tbl       = (ushort*)d_ws;
        int*    seg_start = (int*)((char*)d_ws + tbl_bytes);
        fill_bounds_kernel<<<(T + 255) / 256, 256, 0, stream>>>(seg_ids, seg_start, T);
        conv_emb_kernel<<<(VV * DD) / (256 * 4), 256, 0, stream>>>(emb, tbl);
        seg_mean_bf16shfl_kernel<<<GRID, THREADS, 0, stream>>>(tokens, seg_start, tbl, pos, out);
    } else {
        seg_mean_embed_bsearch_kernel<<<NSEG, 256, 0, stream>>>(tokens, seg_ids, emb, pos, out, T);
    }
}